// Round 14
// baseline (89.465 us; speedup 1.0000x reference)
//
#include <hip/hip_runtime.h>
#include <hip/hip_bf16.h>
#include <math.h>

// Sizes (fixed by the problem)
#define B 1024
#define L 20
#define D 50
#define M_GAT 5120
#define S_GAT 10
#define ALPHA 0.9f
#define QSCALE 0.14142135623730951f  // 1/sqrt(50)

#define TS 64          // Q tile rows
#define QTC (B / TS)   // 16 q-tiles
#define KVT 64         // KV tile rows
#define NKV (B / KVT)  // 16 KV tiles
#define PST 56         // partial row stride

#define NR (B * L)     // 20480 ggnn rows

typedef __attribute__((ext_vector_type(8))) short short8v;  // 8 bf16 (4 VGPR)
typedef __attribute__((ext_vector_type(4))) float f32x4;

static __device__ inline unsigned short f2bf(float f) {
    __hip_bfloat16 h = __float2bfloat16(f);
    return *reinterpret_cast<unsigned short*>(&h);
}
static __device__ inline float bf2f(unsigned short v) {
    return __uint_as_float(((unsigned)v) << 16);
}
static __device__ inline float sigf(float x) { return 1.f / (1.f + __expf(-x)); }

// ---------------------------------------------------------------------------
// Kernel 0: bf16 weight planes + padded bias vectors + F-table + gat_wT.
// ---------------------------------------------------------------------------
__global__ __launch_bounds__(256) void prep_weights(
    const float* __restrict__ w_in, const float* __restrict__ w_out,
    const float* __restrict__ w_rzh, const float* __restrict__ w_rz_old,
    const float* __restrict__ w_h_old,
    const float* __restrict__ b_in, const float* __restrict__ b_out,
    const float* __restrict__ b_rzh, const float* __restrict__ b_rz_old,
    const float* __restrict__ in_proj_w, const float* __restrict__ in_proj_b,
    const float* __restrict__ out_proj_w, const float* __restrict__ gat_w,
    unsigned short* __restrict__ wAB_bf, unsigned short* __restrict__ wrzh_bf,
    unsigned short* __restrict__ wrz_bf, unsigned short* __restrict__ wh_bf,
    float* __restrict__ biasAB, float* __restrict__ brz_pad, float* __restrict__ brzh_pad,
    unsigned short* __restrict__ wqkv_bf, float* __restrict__ biasqkv,
    unsigned short* __restrict__ wout_bf, float* __restrict__ Ftab,
    float* __restrict__ gat_wT)
{
    const int i = blockIdx.x * 256 + threadIdx.x;
    if (i < 112 * 128) {
        int e = i / 128, j = i % 128;
        float v = 0.f;
        if (e < 50 && j < 50) v = w_in[e * 50 + j];
        else if (e >= 50 && e < 100 && j >= 50 && j < 100) v = w_out[(e - 50) * 50 + (j - 50)];
        wAB_bf[i] = f2bf(v);
    }
    if (i < 192 * 128) {
        int e = i / 128, j = i % 128;
        float v = 0.f;
        int src = -1;
        if (e < 50) src = e;
        else if (e >= 64 && e < 114) src = 50 + (e - 64);
        else if (e >= 128 && e < 178) src = 100 + (e - 128);
        if (src >= 0 && j < 100) v = w_rzh[src * 100 + j];
        wrzh_bf[i] = f2bf(v);
    }
    if (i < 128 * 64) {
        int e = i / 64, d = i % 64;
        float v = 0.f;
        int src = -1;
        if (e < 50) src = e;
        else if (e >= 64 && e < 114) src = 50 + (e - 64);
        if (src >= 0 && d < 50) v = w_rz_old[src * 50 + d];
        wrz_bf[i] = f2bf(v);
    }
    if (i < 64 * 64) {
        int e = i / 64, d = i % 64;
        wh_bf[i] = f2bf((e < 50 && d < 50) ? w_h_old[e * 50 + d] : 0.f);
        wout_bf[i] = f2bf((e < 50 && d < 50) ? out_proj_w[e * 50 + d] : 0.f);
    }
    if (i < 192 * 64) {
        int e = i / 64, d = i % 64;
        float v = 0.f;
        int src = -1;
        if (e < 50) src = e;
        else if (e >= 64 && e < 114) src = 50 + (e - 64);
        else if (e >= 128 && e < 178) src = 100 + (e - 128);
        if (src >= 0 && d < 50) v = in_proj_w[src * 50 + d];
        wqkv_bf[i] = f2bf(v);
    }
    if (i < 192) {
        int src = -1;
        if (i < 50) src = i;
        else if (i >= 64 && i < 114) src = 50 + (i - 64);
        else if (i >= 128 && i < 178) src = 100 + (i - 128);
        biasqkv[i] = (src >= 0) ? in_proj_b[src] : 0.f;
    }
    if (i < 112) biasAB[i] = (i < 50) ? b_in[i] : ((i < 100) ? b_out[i - 50] : 0.f);
    if (i < 128) brz_pad[i] = (i < 50) ? b_rz_old[i] : ((i >= 64 && i < 114) ? b_rz_old[50 + i - 64] : 0.f);
    if (i < 192) brzh_pad[i] = (i < 50) ? b_rzh[i]
                              : ((i >= 64 && i < 114) ? b_rzh[50 + i - 64]
                              : ((i >= 128 && i < 178) ? b_rzh[100 + i - 128] : 0.f));
    if (i < 400) {
        int l = i / 20, t = i % 20;
        Ftab[i] = (1.f + 2.f * cosf(6.283185307179586f * (float)(l - t) / 20.f)) * 0.05f;
    }
    if (i < 50 * 64) {
        int d = i / 64, e = i % 64;
        gat_wT[i] = (e < 50) ? gat_w[e * 50 + d] : 0.f;
    }
}

// ===========================================================================
// Stage-1 fused kernel: emb_qkv (320) | ggnn_pre (1024) | gat 4m/blk (1280)
// ===========================================================================
#define K1_SMEM 27648

__device__ __forceinline__ void emb_qkv_body(
    unsigned char* sm, int st, int l, int tid,
    const float* __restrict__ item_emb, const float* __restrict__ pop_emb,
    const int* __restrict__ input_session, const int* __restrict__ input_pop,
    const unsigned short* __restrict__ wqkv_bf, const float* __restrict__ biasqkv,
    float* __restrict__ emb_ws,
    unsigned short* __restrict__ Qp, unsigned short* __restrict__ Kp,
    unsigned short* __restrict__ VTp)
{
    const int s0 = st * 64;
    const int wid = tid >> 6, lane = tid & 63;
    const int lr = lane & 15, kg = lane >> 4;
    const int wl = wid * 16;

    int* isl = (int*)sm;                                           // 256 B
    int* ipl = (int*)(sm + 256);                                   // 256 B
    unsigned short (*sa)[72]   = (unsigned short(*)[72])(sm + 512);    // 9216 B
    unsigned short (*sqkv)[136] = (unsigned short(*)[136])(sm + 9728); // 17408 B

    if (tid < 64) {
        isl[tid] = input_session[(s0 + tid) * L + l];
        ipl[tid] = input_pop[(s0 + tid) * L + l];
    }
    __syncthreads();
    for (int i = tid; i < 64 * 64; i += 256) {
        const int r = i >> 6, d = i & 63;
        float v = 0.f;
        if (d < 50) {
            v = item_emb[(size_t)isl[r] * 50 + d] + pop_emb[(size_t)ipl[r] * 50 + d];
            emb_ws[((size_t)(s0 + r) * L + l) * 50 + d] = v;
        }
        sa[r][d] = f2bf(v);
    }
    __syncthreads();

    const short8v ax0 = *(const short8v*)&sa[wl + lr][kg * 8];
    const short8v ax1 = *(const short8v*)&sa[wl + lr][32 + kg * 8];

    f32x4 acc[12];
    #pragma unroll
    for (int ct = 0; ct < 12; ++ct) {
        const unsigned short* wrow = wqkv_bf + ((size_t)(ct * 16 + lr)) * 64;
        const short8v wb0 = *(const short8v*)(wrow + kg * 8);
        const short8v wb1 = *(const short8v*)(wrow + 32 + kg * 8);
        f32x4 z = (f32x4){0.f, 0.f, 0.f, 0.f};
        z = __builtin_amdgcn_mfma_f32_16x16x32_bf16(ax0, wb0, z, 0, 0, 0);
        z = __builtin_amdgcn_mfma_f32_16x16x32_bf16(ax1, wb1, z, 0, 0, 0);
        acc[ct] = z;
    }

    #pragma unroll
    for (int ct = 0; ct < 8; ++ct) {
        const int e = ct * 16 + lr;
        const float bb = biasqkv[e];
        #pragma unroll
        for (int j = 0; j < 4; ++j) {
            float v = acc[ct][j] + bb;
            if (ct < 4) v *= QSCALE;
            sqkv[wl + kg * 4 + j][e] = f2bf(v);
        }
    }
    #pragma unroll
    for (int ct = 8; ct < 12; ++ct) {
        const int d = ct * 16 + lr - 128;
        const float bb = biasqkv[ct * 16 + lr];
        ushort4 pk;
        pk.x = f2bf(acc[ct][0] + bb);
        pk.y = f2bf(acc[ct][1] + bb);
        pk.z = f2bf(acc[ct][2] + bb);
        pk.w = f2bf(acc[ct][3] + bb);
        if (d == 50) { pk.x = 0x3F80; pk.y = 0x3F80; pk.z = 0x3F80; pk.w = 0x3F80; }
        *(ushort4*)(VTp + ((size_t)l * 64 + d) * B + s0 + wl + kg * 4) = pk;
    }
    __syncthreads();
    for (int i = tid; i < 1024; i += 256) {
        const int r = i >> 4, c = i & 15;
        const size_t rowb = ((size_t)l * B + s0 + r) * 64;
        if (c < 8) *(uint4*)(Qp + rowb + c * 8) = *(const uint4*)&sqkv[r][c * 8];
        else       *(uint4*)(Kp + rowb + (c - 8) * 8) = *(const uint4*)&sqkv[r][64 + (c - 8) * 8];
    }
}

__device__ __forceinline__ void ggnn_pre_body(
    unsigned char* sm, int b, int tid,
    const float* __restrict__ item_emb, const int* __restrict__ node_items,
    const float* __restrict__ A,
    unsigned short* __restrict__ hx_bf, unsigned short* __restrict__ h_bf)
{
    float (*Ash)[2 * L] = (float(*)[2 * L])sm;          // 3200 B
    float (*hsh)[D]     = (float(*)[D])(sm + 3200);     // 4000 B

    for (int i = tid; i < L * 2 * L; i += 256)
        Ash[i / (2 * L)][i % (2 * L)] = A[(size_t)b * L * 2 * L + i];
    for (int i = tid; i < L * D; i += 256) {
        int n = i / D, d = i % D;
        hsh[n][d] = item_emb[(size_t)node_items[b * L + n] * D + d];
    }
    __syncthreads();
    for (int i = tid; i < L * 64; i += 256) {
        int n = i >> 6, c = i & 63;
        h_bf[((size_t)b * L + n) * 64 + c] = (c < 50) ? f2bf(hsh[n][c]) : (unsigned short)0;
    }
    for (int i = tid; i < L * 128; i += 256) {
        int n = i >> 7, c = i & 127;
        float v = 0.f;
        if (c < 50) {
            #pragma unroll
            for (int m = 0; m < L; ++m) v += Ash[n][m] * hsh[m][c];
        } else if (c < 100) {
            const int cc = c - 50;
            #pragma unroll
            for (int m = 0; m < L; ++m) v += Ash[n][L + m] * hsh[m][cc];
        }
        hx_bf[((size_t)b * L + n) * 128 + c] = f2bf(v);
    }
}

// gat: wave-parallel, no barriers, 4 m per block (1 per wave).
__device__ __forceinline__ void gat_body(
    unsigned char* sm, int mb, int tid,
    const float* __restrict__ self_vecs, const float* __restrict__ neigh_vecs,
    const float* __restrict__ gat_wT, const float* __restrict__ gat_b,
    float* __restrict__ out_gat)
{
    const int wid = tid >> 6, lane = tid & 63;
    const int m = mb * 4 + wid;
    float (*ctx_lds)[64] = (float(*)[64])sm;   // 1024 B

    const float sv = (lane < D) ? self_vecs[(size_t)m * D + lane] : 0.f;
    float nv[S_GAT];
    #pragma unroll
    for (int s = 0; s < S_GAT; ++s)
        nv[s] = (lane < D) ? neigh_vecs[((size_t)m * S_GAT + s) * D + lane] : 0.f;

    float sc[S_GAT + 1];
    #pragma unroll
    for (int s = 0; s < S_GAT; ++s) {
        float p = sv * nv[s];
        #pragma unroll
        for (int mk = 1; mk < 64; mk <<= 1) p += __shfl_xor(p, mk);
        sc[s] = p;
    }
    {
        float p = sv * sv;
        #pragma unroll
        for (int mk = 1; mk < 64; mk <<= 1) p += __shfl_xor(p, mk);
        sc[S_GAT] = p;
    }
    float mx = sc[0];
    #pragma unroll
    for (int s = 1; s < S_GAT + 1; ++s) mx = fmaxf(mx, sc[s]);
    float sum = 0.f;
    #pragma unroll
    for (int s = 0; s < S_GAT + 1; ++s) { sc[s] = __expf(sc[s] - mx); sum += sc[s]; }
    const float inv = 1.f / sum;
    float ctx = sc[S_GAT] * sv;
    #pragma unroll
    for (int s = 0; s < S_GAT; ++s) ctx += sc[s] * nv[s];
    ctx *= inv;
    ctx_lds[wid][lane] = ctx;   // wave-private row; no block barrier needed

    float o = (lane < D) ? gat_b[lane] : 0.f;
    #pragma unroll 10
    for (int d = 0; d < D; ++d)
        o += gat_wT[d * 64 + lane] * ctx_lds[wid][d];
    if (lane < D)
        out_gat[(size_t)m * D + lane] = fmaxf(o, 0.f);
}

__global__ __launch_bounds__(256) void stage1_kernel(
    const float* __restrict__ item_emb, const float* __restrict__ pop_emb,
    const int* __restrict__ input_session, const int* __restrict__ input_pop,
    const unsigned short* __restrict__ wqkv_bf, const float* __restrict__ biasqkv,
    float* __restrict__ emb_ws,
    unsigned short* __restrict__ Qp, unsigned short* __restrict__ Kp,
    unsigned short* __restrict__ VTp,
    const int* __restrict__ node_items, const float* __restrict__ A,
    unsigned short* __restrict__ hx_bf, unsigned short* __restrict__ h_bf,
    const float* __restrict__ self_vecs, const float* __restrict__ neigh_vecs,
    const float* __restrict__ gat_wT, const float* __restrict__ gat_b,
    float* __restrict__ out_gat)
{
    __shared__ __align__(16) unsigned char sm[K1_SMEM];
    const int bid = blockIdx.x, tid = threadIdx.x;
    if (bid < 320) {
        emb_qkv_body(sm, bid % 16, bid / 16, tid,
                     item_emb, pop_emb, input_session, input_pop,
                     wqkv_bf, biasqkv, emb_ws, Qp, Kp, VTp);
    } else if (bid < 1344) {
        ggnn_pre_body(sm, bid - 320, tid, item_emb, node_items, A, hx_bf, h_bf);
    } else {
        gat_body(sm, bid - 1344, tid, self_vecs, neigh_vecs, gat_wT, gat_b, out_gat);
    }
}

// ===========================================================================
// Stage-2 fused kernel: attn_mfma (320*ns, XCD-swizzled) | ggnn_main (320)
// | dsp (1024). LDS union 27648 B -> 5 blocks/CU.
// ===========================================================================
#define K2_SMEM 27648

__device__ __forceinline__ void attn_mfma_body(
    unsigned char* sm, int qt, int l, int sp, int tid,
    const unsigned short* __restrict__ Qp, const unsigned short* __restrict__ Kp,
    const unsigned short* __restrict__ VTp, float* __restrict__ part,
    int ns, int tps)
{
    const int s0 = qt * TS;
    const int wid = tid >> 6, lane = tid & 63;
    const int lr = lane & 15, kg = lane >> 4;

    unsigned short (*Klds)[72] = (unsigned short(*)[72])sm;               // 9216
    unsigned short (*Vlds)[72] = (unsigned short(*)[72])(sm + 9216);      // 9216
    unsigned short (*Plds)[16][72] = (unsigned short(*)[16][72])(sm + 18432); // 9216

    const unsigned short* qrow = Qp + ((size_t)l * B + s0 + wid * 16 + lr) * 64;
    const short8v qa0 = *(const short8v*)(qrow + kg * 8);
    const short8v qa1 = *(const short8v*)(qrow + 32 + kg * 8);

    const unsigned short* kbase = Kp + (size_t)l * B * 64;
    const unsigned short* vbase = VTp + (size_t)l * 64 * B;
    const int r0 = tid >> 3, c0 = (tid & 7) * 8;   // r0 in 0..31

    f32x4 oacc[4];
    #pragma unroll
    for (int j = 0; j < 4; ++j) oacc[j] = (f32x4){0.f, 0.f, 0.f, 0.f};

    uint4 kA, kB, vA, vB;
    const int t0 = sp * tps;
    {   // prologue prefetch of first tile
        const unsigned short* ks = kbase + (size_t)(t0 * KVT) * 64;
        const unsigned short* vs = vbase + (size_t)(t0 * KVT);
        kA = *(const uint4*)(ks + (size_t)r0 * 64 + c0);
        kB = *(const uint4*)(ks + (size_t)(r0 + 32) * 64 + c0);
        vA = *(const uint4*)(vs + (size_t)r0 * B + c0);
        vB = *(const uint4*)(vs + (size_t)(r0 + 32) * B + c0);
    }

    for (int tt = t0; tt < t0 + tps; ++tt) {
        __syncthreads();   // prior tile's LDS reads complete
        *(uint4*)&Klds[r0][c0]      = kA;
        *(uint4*)&Klds[r0 + 32][c0] = kB;
        *(uint4*)&Vlds[r0][c0]      = vA;
        *(uint4*)&Vlds[r0 + 32][c0] = vB;
        __syncthreads();

        if (tt + 1 < t0 + tps) {   // prefetch next tile; waits overlap compute
            const unsigned short* ks = kbase + (size_t)((tt + 1) * KVT) * 64;
            const unsigned short* vs = vbase + (size_t)((tt + 1) * KVT);
            kA = *(const uint4*)(ks + (size_t)r0 * 64 + c0);
            kB = *(const uint4*)(ks + (size_t)(r0 + 32) * 64 + c0);
            vA = *(const uint4*)(vs + (size_t)r0 * B + c0);
            vB = *(const uint4*)(vs + (size_t)(r0 + 32) * B + c0);
        }

        // S = Q @ K^T (8 MFMA), P = exp(S) -> LDS
        #pragma unroll
        for (int ct = 0; ct < 4; ++ct) {
            const short8v kb0 = *(const short8v*)&Klds[ct * 16 + lr][kg * 8];
            const short8v kb1 = *(const short8v*)&Klds[ct * 16 + lr][32 + kg * 8];
            f32x4 z = (f32x4){0.f, 0.f, 0.f, 0.f};
            z = __builtin_amdgcn_mfma_f32_16x16x32_bf16(qa0, kb0, z, 0, 0, 0);
            z = __builtin_amdgcn_mfma_f32_16x16x32_bf16(qa1, kb1, z, 0, 0, 0);
            #pragma unroll
            for (int j = 0; j < 4; ++j)
                Plds[wid][kg * 4 + j][ct * 16 + lr] = f2bf(__expf(z[j]));
        }

        // O += P @ V (8 MFMA); V ones-column at d=50 accumulates sum(P)
        const short8v pa0 = *(const short8v*)&Plds[wid][lr][kg * 8];
        const short8v pa1 = *(const short8v*)&Plds[wid][lr][32 + kg * 8];
        #pragma unroll
        for (int ct = 0; ct < 4; ++ct) {
            const short8v vb0 = *(const short8v*)&Vlds[ct * 16 + lr][kg * 8];
            const short8v vb1 = *(const short8v*)&Vlds[ct * 16 + lr][32 + kg * 8];
            oacc[ct] = __builtin_amdgcn_mfma_f32_16x16x32_bf16(pa0, vb0, oacc[ct], 0, 0, 0);
            oacc[ct] = __builtin_amdgcn_mfma_f32_16x16x32_bf16(pa1, vb1, oacc[ct], 0, 0, 0);
        }
    }

    const size_t pbase = (((size_t)(l * QTC + qt) * ns + sp) * TS) * PST;
    #pragma unroll
    for (int j = 0; j < 4; ++j) {
        const int row = wid * 16 + kg * 4 + j;
        const size_t rowb = pbase + (size_t)row * PST;
        #pragma unroll
        for (int ct = 0; ct < 4; ++ct) {
            const int d = ct * 16 + lr;
            if (d < 52) part[rowb + d] = oacc[ct][j];
        }
    }
}

__device__ __forceinline__ void dsp_body(
    unsigned char* sm, int b, int tid,
    const float* __restrict__ emb_ws, const float* __restrict__ Ftab,
    const float* __restrict__ beta,
    const float* __restrict__ ln_w, const float* __restrict__ ln_b,
    float* __restrict__ dsp_ws)
{
    const int wid = tid >> 6, lane = tid & 63;
    float (*se)[D] = (float(*)[D])sm;              // 4000
    float (*sy)[D] = (float(*)[D])(sm + 4000);     // 4000
    float (*F)[L]  = (float(*)[L])(sm + 8000);     // 1600

    for (int i = tid; i < L * D; i += 256) se[i / D][i % D] = emb_ws[(size_t)b * L * D + i];
    for (int i = tid; i < L * L; i += 256) (&F[0][0])[i] = Ftab[i];
    __syncthreads();
    for (int i = tid; i < L * D; i += 256) {
        int l = i / D, d = i % D;
        float low = 0.f;
        #pragma unroll
        for (int t = 0; t < L; ++t) low += F[l][t] * se[t][d];
        float be = beta[d], b2 = be * be;
        sy[l][d] = (1.f - b2) * low + (1.f + b2) * se[l][d];
    }
    __syncthreads();
    for (int l = wid; l < L; l += 4) {
        float x = (lane < D) ? sy[l][lane] : 0.f;
        float s = x;
        #pragma unroll
        for (int mk = 1; mk < 64; mk <<= 1) s += __shfl_xor(s, mk);
        const float mu = s * (1.f / (float)D);
        const float xm = (lane < D) ? (x - mu) : 0.f;
        float v = xm * xm;
        #pragma unroll
        for (int mk = 1; mk < 64; mk <<= 1) v += __shfl_xor(v, mk);
        const float rs = rsqrtf(v * (1.f / (float)D) + 1e-12f);
        if (lane < D)
            dsp_ws[((size_t)b * L + l) * D + lane] = ALPHA * (ln_w[lane] * xm * rs + ln_b[lane]);
    }
}

// ggnn_main with sx reuse (hinp overwrites xin; 26.6 KB LDS).
__device__ __forceinline__ void ggnn_main_body(
    unsigned char* sm, int blk, int tid,
    const unsigned short* __restrict__ hx_bf, const unsigned short* __restrict__ h_bf,
    const unsigned short* __restrict__ wAB_bf, const unsigned short* __restrict__ wrzh_bf,
    const unsigned short* __restrict__ wrz_bf, const unsigned short* __restrict__ wh_bf,
    const float* __restrict__ biasAB, const float* __restrict__ brz_pad,
    const float* __restrict__ brzh_pad, const float* __restrict__ b_h_old,
    float* __restrict__ out_ggnn)
{
    const int wid = tid >> 6, lane = tid & 63;
    const int lr = lane & 15, kg = lane >> 4;
    const int wl = wid * 16;
    const int rblk = blk * 64;

    unsigned short (*sx)[136]  = (unsigned short(*)[136])sm;             // 17408
    unsigned short (*shh)[72]  = (unsigned short(*)[72])(sm + 17408);    // 9216

    for (int i = tid; i < 1024; i += 256) {
        const int r = i >> 4, c = i & 15;
        *(uint4*)&sx[r][c * 8] = *(const uint4*)(hx_bf + ((size_t)(rblk + r)) * 128 + c * 8);
    }
    for (int i = tid; i < 512; i += 256) {
        const int r = i >> 3, c = i & 7;
        *(uint4*)&shh[r][c * 8] = *(const uint4*)(h_bf + ((size_t)(rblk + r)) * 64 + c * 8);
    }
    __syncthreads();

    short8v ax[4];
    #pragma unroll
    for (int t = 0; t < 4; ++t) ax[t] = *(const short8v*)&sx[wl + lr][t * 32 + kg * 8];
    f32x4 acc1[7];
    #pragma unroll
    for (int ct = 0; ct < 7; ++ct) {
        f32x4 z = (f32x4){0.f, 0.f, 0.f, 0.f};
        #pragma unroll
        for (int t = 0; t < 4; ++t) {
            const short8v wb = *(const short8v*)(wAB_bf + ((size_t)(ct * 16 + lr)) * 128 + t * 32 + kg * 8);
            z = __builtin_amdgcn_mfma_f32_16x16x32_bf16(ax[t], wb, z, 0, 0, 0);
        }
        acc1[ct] = z;
    }
    #pragma unroll
    for (int ct = 0; ct < 7; ++ct) {
        const float bb = biasAB[ct * 16 + lr];
        #pragma unroll
        for (int j = 0; j < 4; ++j)
            sx[wl + kg * 4 + j][ct * 16 + lr] = f2bf(acc1[ct][j] + bb);
    }

    short8v ah[4];
    #pragma unroll
    for (int t = 0; t < 4; ++t) ah[t] = *(const short8v*)&sx[wl + lr][t * 32 + kg * 8];
    f32x4 acc2[12];
    #pragma unroll
    for (int ct = 0; ct < 12; ++ct) {
        f32x4 z = (f32x4){0.f, 0.f, 0.f, 0.f};
        #pragma unroll
        for (int t = 0; t < 4; ++t) {
            const short8v wb = *(const short8v*)(wrzh_bf + ((size_t)(ct * 16 + lr)) * 128 + t * 32 + kg * 8);
            z = __builtin_amdgcn_mfma_f32_16x16x32_bf16(ah[t], wb, z, 0, 0, 0);
        }
        acc2[ct] = z;
    }
    short8v ahh[2];
    #pragma unroll
    for (int t = 0; t < 2; ++t) ahh[t] = *(const short8v*)&shh[wl + lr][t * 32 + kg * 8];
    f32x4 acc3[8];
    #pragma unroll
    for (int ct = 0; ct < 8; ++ct) {
        f32x4 z = (f32x4){0.f, 0.f, 0.f, 0.f};
        #pragma unroll
        for (int t = 0; t < 2; ++t) {
            const short8v wb = *(const short8v*)(wrz_bf + ((size_t)(ct * 16 + lr)) * 64 + t * 32 + kg * 8);
            z = __builtin_amdgcn_mfma_f32_16x16x32_bf16(ahh[t], wb, z, 0, 0, 0);
        }
        acc3[ct] = z;
    }

    #pragma unroll
    for (int ct = 0; ct < 4; ++ct) {
        const int e = ct * 16 + lr;
        const float br = brz_pad[e], brh = brzh_pad[e];
        #pragma unroll
        for (int j = 0; j < 4; ++j) {
            const float reset = sigf(acc3[ct][j] + br + acc2[ct][j] + brh);
            const float hval = bf2f(shh[wl + kg * 4 + j][e]);
            sx[wl + kg * 4 + j][e] = f2bf(reset * hval);
        }
    }

    short8v ar[2];
    #pragma unroll
    for (int t = 0; t < 2; ++t) ar[t] = *(const short8v*)&sx[wl + lr][t * 32 + kg * 8];
    f32x4 acc4[4];
    #pragma unroll
    for (int ct = 0; ct < 4; ++ct) {
        f32x4 z = (f32x4){0.f, 0.f, 0.f, 0.f};
        #pragma unroll
        for (int t = 0; t < 2; ++t) {
            const short8v wb = *(const short8v*)(wh_bf + ((size_t)(ct * 16 + lr)) * 64 + t * 32 + kg * 8);
            z = __builtin_amdgcn_mfma_f32_16x16x32_bf16(ar[t], wb, z, 0, 0, 0);
        }
        acc4[ct] = z;
    }

    #pragma unroll
    for (int ct = 0; ct < 4; ++ct) {
        const int e = ct * 16 + lr;
        if (e < 50) {
            const float brz_z = brz_pad[64 + e], brh_z = brzh_pad[64 + e];
            const float brh_h = brzh_pad[128 + e], bh = b_h_old[e];
            #pragma unroll
            for (int j = 0; j < 4; ++j) {
                const int rl = wl + kg * 4 + j;
                const float zg = sigf(acc3[4 + ct][j] + brz_z + acc2[4 + ct][j] + brh_z);
                const float hn = tanhf(acc2[8 + ct][j] + brh_h + acc4[ct][j] + bh);
                const float hval = bf2f(shh[rl][e]);
                out_ggnn[(size_t)(rblk + rl) * D + e] = (1.f - zg) * hval + zg * hn;
            }
        }
    }
}

__global__ __launch_bounds__(256) void stage2_kernel(
    const unsigned short* __restrict__ Qp, const unsigned short* __restrict__ Kp,
    const unsigned short* __restrict__ VTp, float* __restrict__ part,
    int ns, int tps,
    const float* __restrict__ emb_ws, const float* __restrict__ Ftab,
    const float* __restrict__ beta,
    const float* __restrict__ ln_w, const float* __restrict__ ln_b,
    float* __restrict__ dsp_ws,
    const unsigned short* __restrict__ hx_bf, const unsigned short* __restrict__ h_bf,
    const unsigned short* __restrict__ wAB_bf, const unsigned short* __restrict__ wrzh_bf,
    const unsigned short* __restrict__ wrz_bf, const unsigned short* __restrict__ wh_bf,
    const float* __restrict__ biasAB, const float* __restrict__ brz_pad,
    const float* __restrict__ brzh_pad, const float* __restrict__ b_h_old,
    float* __restrict__ out_ggnn)
{
    __shared__ __align__(16) unsigned char sm[K2_SMEM];
    const int bid = blockIdx.x, tid = threadIdx.x;
    const int attnB = 320 * ns;
    if (bid < attnB) {
        // XCD-aware bijective swizzle (attnB % 8 == 0): each XCD gets a
        // contiguous chunk of logical blocks -> same-l K/V panels stay in
        // one XCD's L2 instead of being refetched by all 8.
        const int lb = (bid & 7) * (attnB >> 3) + (bid >> 3);
        const int sp = lb / 320, rem = lb % 320;
        attn_mfma_body(sm, rem % 16, rem / 16, sp, tid, Qp, Kp, VTp, part, ns, tps);
    } else if (bid < attnB + 320) {
        ggnn_main_body(sm, bid - attnB, tid, hx_bf, h_bf, wAB_bf, wrzh_bf,
                       wrz_bf, wh_bf, biasAB, brz_pad, brzh_pad, b_h_old, out_ggnn);
    } else {
        dsp_body(sm, bid - attnB - 320, tid, emb_ws, Ftab, beta, ln_w, ln_b, dsp_ws);
    }
}

// ===========================================================================
// Stage-3 kernel: attn_reduce (320)
// ===========================================================================
__global__ __launch_bounds__(256) void stage3_kernel(
    const float* __restrict__ part,
    const unsigned short* __restrict__ wout_bf, const float* __restrict__ out_b,
    const float* __restrict__ dsp_ws, float* __restrict__ out_hidden, int ns)
{
    const int bid = blockIdx.x, tid = threadIdx.x;
    const int qt = bid % 16, l = bid / 16;
    const int s0 = qt * TS;
    const int wid = tid >> 6, lane = tid & 63;
    const int lr = lane & 15, kg = lane >> 4;
    const int wl = wid * 16;

    __shared__ unsigned short ca[64][72];

    const size_t pbase = ((size_t)(l * QTC + qt) * ns) * TS * PST;

    for (int i = tid; i < 1024; i += 256) {
        const int row = i >> 4, c4 = i & 15;
        const int col = c4 * 4;
        if (col >= 52) {
            ca[row][col] = 0; ca[row][col + 1] = 0;
            ca[row][col + 2] = 0; ca[row][col + 3] = 0;
            continue;
        }
        float4 a = make_float4(0.f, 0.f, 0.f, 0.f);
        float lsum = 0.f;
        for (int sp = 0; sp < ns; ++sp) {
            const size_t rb = pbase + ((size_t)sp * TS + row) * PST;
            lsum += part[rb + 50];
            float4 p = *(const float4*)&part[rb + col];
            a.x += p.x; a.y += p.y; a.z += p.z; a.w += p.w;
        }
        const float inv = 1.f / lsum;
        ca[row][col]     = f2bf(a.x * inv);
        ca[row][col + 1] = f2bf(a.y * inv);
        ca[row][col + 2] = f2bf(a.z * inv);
        ca[row][col + 3] = f2bf(a.w * inv);
    }
    __syncthreads();

    const short8v a0 = *(const short8v*)&ca[wl + lr][kg * 8];
    const short8v a1 = *(const short8v*)&ca[wl + lr][32 + kg * 8];
    f32x4 acc[4];
    #pragma unroll
    for (int ct = 0; ct < 4; ++ct) {
        const unsigned short* wrow = wout_bf + ((size_t)(ct * 16 + lr)) * 64;
        const short8v wb0 = *(const short8v*)(wrow + kg * 8);
        const short8v wb1 = *(const short8v*)(wrow + 32 + kg * 8);
        f32x4 z = (f32x4){0.f, 0.f, 0.f, 0.f};
        z = __builtin_amdgcn_mfma_f32_16x16x32_bf16(a0, wb0, z, 0, 0, 0);
        z = __builtin_amdgcn_mfma_f32_16x16x32_bf16(a1, wb1, z, 0, 0, 0);
        acc[ct] = z;
    }
    #pragma unroll
    for (int ct = 0; ct < 4; ++ct) {
        const int e = ct * 16 + lr;
        if (e < 50) {
            const float bb = out_b[e];
            #pragma unroll
            for (int j = 0; j < 4; ++j) {
                const int s = s0 + wl + kg * 4 + j;
                const size_t base = ((size_t)s * L + l) * D;
                out_hidden[base + e] = dsp_ws[base + e] + (1.f - ALPHA) * (acc[ct][j] + bb);
            }
        }
    }
}

// ---------------------------------------------------------------------------
extern "C" void kernel_launch(void* const* d_in, const int* in_sizes, int n_in,
                              void* d_out, int out_size, void* d_ws, size_t ws_size,
                              hipStream_t stream)
{
    const float* item_emb   = (const float*)d_in[0];
    const float* pop_emb    = (const float*)d_in[1];
    const float* beta       = (const float*)d_in[2];
    const float* ln_w       = (const float*)d_in[3];
    const float* ln_b       = (const float*)d_in[4];
    const float* in_proj_w  = (const float*)d_in[5];
    const float* in_proj_b  = (const float*)d_in[6];
    const float* out_proj_w = (const float*)d_in[7];
    const float* out_proj_b = (const float*)d_in[8];
    const float* w_in       = (const float*)d_in[9];
    const float* b_in       = (const float*)d_in[10];
    const float* w_out      = (const float*)d_in[11];
    const float* b_out      = (const float*)d_in[12];
    const float* w_rzh      = (const float*)d_in[13];
    const float* b_rzh      = (const float*)d_in[14];
    const float* w_rz_old   = (const float*)d_in[15];
    const float* b_rz_old   = (const float*)d_in[16];
    const float* w_h_old    = (const float*)d_in[17];
    const float* b_h_old    = (const float*)d_in[18];
    const float* gat_w      = (const float*)d_in[19];
    const float* gat_b      = (const float*)d_in[20];
    const float* A          = (const float*)d_in[21];
    const float* self_vecs  = (const float*)d_in[22];
    const float* neigh_vecs = (const float*)d_in[23];
    const int* input_session = (const int*)d_in[24];
    const int* input_pop     = (const int*)d_in[25];
    const int* node_items    = (const int*)d_in[26];

    float* ws = (float*)d_ws;
    float* emb_ws = ws;                                   // 1,024,000 f
    float* dsp_ws = ws + (size_t)1024000;                 // 1,024,000 f
    unsigned short* Qp  = (unsigned short*)(ws + 2048000);
    unsigned short* Kp  = Qp + (size_t)L * B * 64;
    unsigned short* VTp = Kp + (size_t)L * B * 64;
    unsigned short* hx_bf = (unsigned short*)(ws + 4014080);    // NR*128 us
    unsigned short* h_bf  = hx_bf + (size_t)NR * 128;           // NR*64 us
    unsigned short* wAB_bf  = h_bf + (size_t)NR * 64;           // 112*128
    unsigned short* wrzh_bf = wAB_bf + 112 * 128;               // 192*128
    unsigned short* wrz_bf  = wrzh_bf + 192 * 128;              // 128*64
    unsigned short* wh_bf   = wrz_bf + 128 * 64;                // 64*64
    float* biasAB   = (float*)(wh_bf + 64 * 64);                // 112
    float* brz_pad  = biasAB + 112;                             // 128
    float* brzh_pad = brz_pad + 128;                            // 192
    unsigned short* wqkv_bf = (unsigned short*)(brzh_pad + 192); // 192*64 us
    unsigned short* wout_bf = wqkv_bf + 192 * 64;                // 64*64 us
    float* biasqkv = (float*)(wout_bf + 64 * 64);                // 192 f
    float* Ftab = biasqkv + 192;                                 // 400 f
    float* gat_wT = Ftab + 400;                                  // 3200 f
    float* part = gat_wT + 3200;

    const size_t base_f = (size_t)(part - ws);
    int ns = 1;
    for (int cand = 8; cand >= 1; cand >>= 1) {
        size_t need = (base_f + (size_t)L * QTC * cand * TS * PST) * 4;
        if (ws_size >= need) { ns = cand; break; }
    }
    const int tps = NKV / ns;   // KV tiles (of 64 rows) per split

    float* out_hidden = (float*)d_out;
    float* out_ggnn   = out_hidden + (size_t)B * L * D;
    float* out_gat    = out_hidden + (size_t)2 * B * L * D;

    prep_weights<<<96, 256, 0, stream>>>(w_in, w_out, w_rzh, w_rz_old, w_h_old,
                                         b_in, b_out, b_rzh, b_rz_old,
                                         in_proj_w, in_proj_b, out_proj_w, gat_w,
                                         wAB_bf, wrzh_bf, wrz_bf, wh_bf,
                                         biasAB, brz_pad, brzh_pad,
                                         wqkv_bf, biasqkv, wout_bf, Ftab, gat_wT);
    stage1_kernel<<<320 + 1024 + (M_GAT / 4), 256, 0, stream>>>(
        item_emb, pop_emb, input_session, input_pop, wqkv_bf, biasqkv,
        emb_ws, Qp, Kp, VTp,
        node_items, A, hx_bf, h_bf,
        self_vecs, neigh_vecs, gat_wT, gat_b, out_gat);
    stage2_kernel<<<320 * ns + 320 + 1024, 256, 0, stream>>>(
        Qp, Kp, VTp, part, ns, tps,
        emb_ws, Ftab, beta, ln_w, ln_b, dsp_ws,
        hx_bf, h_bf, wAB_bf, wrzh_bf, wrz_bf, wh_bf,
        biasAB, brz_pad, brzh_pad, b_h_old, out_ggnn);
    stage3_kernel<<<320, 256, 0, stream>>>(
        part, wout_bf, out_proj_b, dsp_ws, out_hidden, ns);
}

// Round 15
// 83.047 us; speedup vs baseline: 1.0773x; 1.0773x over previous
//
#include <hip/hip_runtime.h>
#include <hip/hip_bf16.h>
#include <math.h>

// Sizes (fixed by the problem)
#define B 1024
#define L 20
#define D 50
#define M_GAT 5120
#define S_GAT 10
#define ALPHA 0.9f
#define QSCALE 0.14142135623730951f  // 1/sqrt(50)

#define TS 64          // Q tile rows
#define QTC (B / TS)   // 16 q-tiles
#define KVT 64         // KV tile rows
#define NKV (B / KVT)  // 16 KV tiles
#define PST 56         // partial row stride

#define NR (B * L)     // 20480 ggnn rows

typedef __attribute__((ext_vector_type(8))) short short8v;  // 8 bf16 (4 VGPR)
typedef __attribute__((ext_vector_type(4))) float f32x4;

static __device__ inline unsigned short f2bf(float f) {
    __hip_bfloat16 h = __float2bfloat16(f);
    return *reinterpret_cast<unsigned short*>(&h);
}
static __device__ inline float bf2f(unsigned short v) {
    return __uint_as_float(((unsigned)v) << 16);
}
static __device__ inline float sigf(float x) { return 1.f / (1.f + __expf(-x)); }

// ---------------------------------------------------------------------------
// Kernel 0: bf16 weight planes + padded bias vectors + F-table + gat_wT.
// ---------------------------------------------------------------------------
__global__ __launch_bounds__(256) void prep_weights(
    const float* __restrict__ w_in, const float* __restrict__ w_out,
    const float* __restrict__ w_rzh, const float* __restrict__ w_rz_old,
    const float* __restrict__ w_h_old,
    const float* __restrict__ b_in, const float* __restrict__ b_out,
    const float* __restrict__ b_rzh, const float* __restrict__ b_rz_old,
    const float* __restrict__ in_proj_w, const float* __restrict__ in_proj_b,
    const float* __restrict__ out_proj_w, const float* __restrict__ gat_w,
    unsigned short* __restrict__ wAB_bf, unsigned short* __restrict__ wrzh_bf,
    unsigned short* __restrict__ wrz_bf, unsigned short* __restrict__ wh_bf,
    float* __restrict__ biasAB, float* __restrict__ brz_pad, float* __restrict__ brzh_pad,
    unsigned short* __restrict__ wqkv_bf, float* __restrict__ biasqkv,
    unsigned short* __restrict__ wout_bf, float* __restrict__ Ftab,
    float* __restrict__ gat_wT)
{
    const int i = blockIdx.x * 256 + threadIdx.x;
    if (i < 112 * 128) {
        int e = i / 128, j = i % 128;
        float v = 0.f;
        if (e < 50 && j < 50) v = w_in[e * 50 + j];
        else if (e >= 50 && e < 100 && j >= 50 && j < 100) v = w_out[(e - 50) * 50 + (j - 50)];
        wAB_bf[i] = f2bf(v);
    }
    if (i < 192 * 128) {
        int e = i / 128, j = i % 128;
        float v = 0.f;
        int src = -1;
        if (e < 50) src = e;
        else if (e >= 64 && e < 114) src = 50 + (e - 64);
        else if (e >= 128 && e < 178) src = 100 + (e - 128);
        if (src >= 0 && j < 100) v = w_rzh[src * 100 + j];
        wrzh_bf[i] = f2bf(v);
    }
    if (i < 128 * 64) {
        int e = i / 64, d = i % 64;
        float v = 0.f;
        int src = -1;
        if (e < 50) src = e;
        else if (e >= 64 && e < 114) src = 50 + (e - 64);
        if (src >= 0 && d < 50) v = w_rz_old[src * 50 + d];
        wrz_bf[i] = f2bf(v);
    }
    if (i < 64 * 64) {
        int e = i / 64, d = i % 64;
        wh_bf[i] = f2bf((e < 50 && d < 50) ? w_h_old[e * 50 + d] : 0.f);
        wout_bf[i] = f2bf((e < 50 && d < 50) ? out_proj_w[e * 50 + d] : 0.f);
    }
    if (i < 192 * 64) {
        int e = i / 64, d = i % 64;
        float v = 0.f;
        int src = -1;
        if (e < 50) src = e;
        else if (e >= 64 && e < 114) src = 50 + (e - 64);
        else if (e >= 128 && e < 178) src = 100 + (e - 128);
        if (src >= 0 && d < 50) v = in_proj_w[src * 50 + d];
        wqkv_bf[i] = f2bf(v);
    }
    if (i < 192) {
        int src = -1;
        if (i < 50) src = i;
        else if (i >= 64 && i < 114) src = 50 + (i - 64);
        else if (i >= 128 && i < 178) src = 100 + (i - 128);
        biasqkv[i] = (src >= 0) ? in_proj_b[src] : 0.f;
    }
    if (i < 112) biasAB[i] = (i < 50) ? b_in[i] : ((i < 100) ? b_out[i - 50] : 0.f);
    if (i < 128) brz_pad[i] = (i < 50) ? b_rz_old[i] : ((i >= 64 && i < 114) ? b_rz_old[50 + i - 64] : 0.f);
    if (i < 192) brzh_pad[i] = (i < 50) ? b_rzh[i]
                              : ((i >= 64 && i < 114) ? b_rzh[50 + i - 64]
                              : ((i >= 128 && i < 178) ? b_rzh[100 + i - 128] : 0.f));
    if (i < 400) {
        int l = i / 20, t = i % 20;
        Ftab[i] = (1.f + 2.f * cosf(6.283185307179586f * (float)(l - t) / 20.f)) * 0.05f;
    }
    if (i < 50 * 64) {
        int d = i / 64, e = i % 64;
        gat_wT[i] = (e < 50) ? gat_w[e * 50 + d] : 0.f;
    }
}

// ===========================================================================
// Stage-1 fused kernel: emb_qkv (320) | ggnn_pre (1024) | gat 4m/blk (1280)
// ===========================================================================
#define K1_SMEM 27648

__device__ __forceinline__ void emb_qkv_body(
    unsigned char* sm, int st, int l, int tid,
    const float* __restrict__ item_emb, const float* __restrict__ pop_emb,
    const int* __restrict__ input_session, const int* __restrict__ input_pop,
    const unsigned short* __restrict__ wqkv_bf, const float* __restrict__ biasqkv,
    float* __restrict__ emb_ws,
    unsigned short* __restrict__ Qp, unsigned short* __restrict__ Kp,
    unsigned short* __restrict__ VTp)
{
    const int s0 = st * 64;
    const int wid = tid >> 6, lane = tid & 63;
    const int lr = lane & 15, kg = lane >> 4;
    const int wl = wid * 16;

    int* isl = (int*)sm;                                           // 256 B
    int* ipl = (int*)(sm + 256);                                   // 256 B
    unsigned short (*sa)[72]   = (unsigned short(*)[72])(sm + 512);    // 9216 B
    unsigned short (*sqkv)[136] = (unsigned short(*)[136])(sm + 9728); // 17408 B

    if (tid < 64) {
        isl[tid] = input_session[(s0 + tid) * L + l];
        ipl[tid] = input_pop[(s0 + tid) * L + l];
    }
    __syncthreads();
    for (int i = tid; i < 64 * 64; i += 256) {
        const int r = i >> 6, d = i & 63;
        float v = 0.f;
        if (d < 50) {
            v = item_emb[(size_t)isl[r] * 50 + d] + pop_emb[(size_t)ipl[r] * 50 + d];
            emb_ws[((size_t)(s0 + r) * L + l) * 50 + d] = v;
        }
        sa[r][d] = f2bf(v);
    }
    __syncthreads();

    const short8v ax0 = *(const short8v*)&sa[wl + lr][kg * 8];
    const short8v ax1 = *(const short8v*)&sa[wl + lr][32 + kg * 8];

    f32x4 acc[12];
    #pragma unroll
    for (int ct = 0; ct < 12; ++ct) {
        const unsigned short* wrow = wqkv_bf + ((size_t)(ct * 16 + lr)) * 64;
        const short8v wb0 = *(const short8v*)(wrow + kg * 8);
        const short8v wb1 = *(const short8v*)(wrow + 32 + kg * 8);
        f32x4 z = (f32x4){0.f, 0.f, 0.f, 0.f};
        z = __builtin_amdgcn_mfma_f32_16x16x32_bf16(ax0, wb0, z, 0, 0, 0);
        z = __builtin_amdgcn_mfma_f32_16x16x32_bf16(ax1, wb1, z, 0, 0, 0);
        acc[ct] = z;
    }

    #pragma unroll
    for (int ct = 0; ct < 8; ++ct) {
        const int e = ct * 16 + lr;
        const float bb = biasqkv[e];
        #pragma unroll
        for (int j = 0; j < 4; ++j) {
            float v = acc[ct][j] + bb;
            if (ct < 4) v *= QSCALE;
            sqkv[wl + kg * 4 + j][e] = f2bf(v);
        }
    }
    #pragma unroll
    for (int ct = 8; ct < 12; ++ct) {
        const int d = ct * 16 + lr - 128;
        const float bb = biasqkv[ct * 16 + lr];
        ushort4 pk;
        pk.x = f2bf(acc[ct][0] + bb);
        pk.y = f2bf(acc[ct][1] + bb);
        pk.z = f2bf(acc[ct][2] + bb);
        pk.w = f2bf(acc[ct][3] + bb);
        if (d == 50) { pk.x = 0x3F80; pk.y = 0x3F80; pk.z = 0x3F80; pk.w = 0x3F80; }
        *(ushort4*)(VTp + ((size_t)l * 64 + d) * B + s0 + wl + kg * 4) = pk;
    }
    __syncthreads();
    for (int i = tid; i < 1024; i += 256) {
        const int r = i >> 4, c = i & 15;
        const size_t rowb = ((size_t)l * B + s0 + r) * 64;
        if (c < 8) *(uint4*)(Qp + rowb + c * 8) = *(const uint4*)&sqkv[r][c * 8];
        else       *(uint4*)(Kp + rowb + (c - 8) * 8) = *(const uint4*)&sqkv[r][64 + (c - 8) * 8];
    }
}

__device__ __forceinline__ void ggnn_pre_body(
    unsigned char* sm, int b, int tid,
    const float* __restrict__ item_emb, const int* __restrict__ node_items,
    const float* __restrict__ A,
    unsigned short* __restrict__ hx_bf, unsigned short* __restrict__ h_bf)
{
    float (*Ash)[2 * L] = (float(*)[2 * L])sm;          // 3200 B
    float (*hsh)[D]     = (float(*)[D])(sm + 3200);     // 4000 B

    for (int i = tid; i < L * 2 * L; i += 256)
        Ash[i / (2 * L)][i % (2 * L)] = A[(size_t)b * L * 2 * L + i];
    for (int i = tid; i < L * D; i += 256) {
        int n = i / D, d = i % D;
        hsh[n][d] = item_emb[(size_t)node_items[b * L + n] * D + d];
    }
    __syncthreads();
    for (int i = tid; i < L * 64; i += 256) {
        int n = i >> 6, c = i & 63;
        h_bf[((size_t)b * L + n) * 64 + c] = (c < 50) ? f2bf(hsh[n][c]) : (unsigned short)0;
    }
    for (int i = tid; i < L * 128; i += 256) {
        int n = i >> 7, c = i & 127;
        float v = 0.f;
        if (c < 50) {
            #pragma unroll
            for (int m = 0; m < L; ++m) v += Ash[n][m] * hsh[m][c];
        } else if (c < 100) {
            const int cc = c - 50;
            #pragma unroll
            for (int m = 0; m < L; ++m) v += Ash[n][L + m] * hsh[m][cc];
        }
        hx_bf[((size_t)b * L + n) * 128 + c] = f2bf(v);
    }
}

// gat: wave-parallel, no barriers, 4 m per block (1 per wave).
__device__ __forceinline__ void gat_body(
    unsigned char* sm, int mb, int tid,
    const float* __restrict__ self_vecs, const float* __restrict__ neigh_vecs,
    const float* __restrict__ gat_wT, const float* __restrict__ gat_b,
    float* __restrict__ out_gat)
{
    const int wid = tid >> 6, lane = tid & 63;
    const int m = mb * 4 + wid;
    float (*ctx_lds)[64] = (float(*)[64])sm;   // 1024 B

    const float sv = (lane < D) ? self_vecs[(size_t)m * D + lane] : 0.f;
    float nv[S_GAT];
    #pragma unroll
    for (int s = 0; s < S_GAT; ++s)
        nv[s] = (lane < D) ? neigh_vecs[((size_t)m * S_GAT + s) * D + lane] : 0.f;

    float sc[S_GAT + 1];
    #pragma unroll
    for (int s = 0; s < S_GAT; ++s) {
        float p = sv * nv[s];
        #pragma unroll
        for (int mk = 1; mk < 64; mk <<= 1) p += __shfl_xor(p, mk);
        sc[s] = p;
    }
    {
        float p = sv * sv;
        #pragma unroll
        for (int mk = 1; mk < 64; mk <<= 1) p += __shfl_xor(p, mk);
        sc[S_GAT] = p;
    }
    float mx = sc[0];
    #pragma unroll
    for (int s = 1; s < S_GAT + 1; ++s) mx = fmaxf(mx, sc[s]);
    float sum = 0.f;
    #pragma unroll
    for (int s = 0; s < S_GAT + 1; ++s) { sc[s] = __expf(sc[s] - mx); sum += sc[s]; }
    const float inv = 1.f / sum;
    float ctx = sc[S_GAT] * sv;
    #pragma unroll
    for (int s = 0; s < S_GAT; ++s) ctx += sc[s] * nv[s];
    ctx *= inv;
    ctx_lds[wid][lane] = ctx;   // wave-private row; no block barrier needed

    float o = (lane < D) ? gat_b[lane] : 0.f;
    #pragma unroll 10
    for (int d = 0; d < D; ++d)
        o += gat_wT[d * 64 + lane] * ctx_lds[wid][d];
    if (lane < D)
        out_gat[(size_t)m * D + lane] = fmaxf(o, 0.f);
}

__global__ __launch_bounds__(256) void stage1_kernel(
    const float* __restrict__ item_emb, const float* __restrict__ pop_emb,
    const int* __restrict__ input_session, const int* __restrict__ input_pop,
    const unsigned short* __restrict__ wqkv_bf, const float* __restrict__ biasqkv,
    float* __restrict__ emb_ws,
    unsigned short* __restrict__ Qp, unsigned short* __restrict__ Kp,
    unsigned short* __restrict__ VTp,
    const int* __restrict__ node_items, const float* __restrict__ A,
    unsigned short* __restrict__ hx_bf, unsigned short* __restrict__ h_bf,
    const float* __restrict__ self_vecs, const float* __restrict__ neigh_vecs,
    const float* __restrict__ gat_wT, const float* __restrict__ gat_b,
    float* __restrict__ out_gat)
{
    __shared__ __align__(16) unsigned char sm[K1_SMEM];
    const int bid = blockIdx.x, tid = threadIdx.x;
    if (bid < 320) {
        emb_qkv_body(sm, bid % 16, bid / 16, tid,
                     item_emb, pop_emb, input_session, input_pop,
                     wqkv_bf, biasqkv, emb_ws, Qp, Kp, VTp);
    } else if (bid < 1344) {
        ggnn_pre_body(sm, bid - 320, tid, item_emb, node_items, A, hx_bf, h_bf);
    } else {
        gat_body(sm, bid - 1344, tid, self_vecs, neigh_vecs, gat_wT, gat_b, out_gat);
    }
}

// ===========================================================================
// Stage-2 fused kernel: attn_mfma (320*ns, XCD-swizzled) | ggnn_main (320)
// | dsp (1024). LDS union 27648 B -> 5 blocks/CU.
// ===========================================================================
#define K2_SMEM 27648

__device__ __forceinline__ void attn_mfma_body(
    unsigned char* sm, int qt, int l, int sp, int tid,
    const unsigned short* __restrict__ Qp, const unsigned short* __restrict__ Kp,
    const unsigned short* __restrict__ VTp, float* __restrict__ part,
    int ns, int tps)
{
    const int s0 = qt * TS;
    const int wid = tid >> 6, lane = tid & 63;
    const int lr = lane & 15, kg = lane >> 4;

    unsigned short (*Klds)[72] = (unsigned short(*)[72])sm;               // 9216
    unsigned short (*Vlds)[72] = (unsigned short(*)[72])(sm + 9216);      // 9216
    unsigned short (*Plds)[16][72] = (unsigned short(*)[16][72])(sm + 18432); // 9216

    const unsigned short* qrow = Qp + ((size_t)l * B + s0 + wid * 16 + lr) * 64;
    const short8v qa0 = *(const short8v*)(qrow + kg * 8);
    const short8v qa1 = *(const short8v*)(qrow + 32 + kg * 8);

    const unsigned short* kbase = Kp + (size_t)l * B * 64;
    const unsigned short* vbase = VTp + (size_t)l * 64 * B;
    const int r0 = tid >> 3, c0 = (tid & 7) * 8;   // r0 in 0..31

    f32x4 oacc[4];
    #pragma unroll
    for (int j = 0; j < 4; ++j) oacc[j] = (f32x4){0.f, 0.f, 0.f, 0.f};

    uint4 kA, kB, vA, vB;
    const int t0 = sp * tps;
    {   // prologue prefetch of first tile
        const unsigned short* ks = kbase + (size_t)(t0 * KVT) * 64;
        const unsigned short* vs = vbase + (size_t)(t0 * KVT);
        kA = *(const uint4*)(ks + (size_t)r0 * 64 + c0);
        kB = *(const uint4*)(ks + (size_t)(r0 + 32) * 64 + c0);
        vA = *(const uint4*)(vs + (size_t)r0 * B + c0);
        vB = *(const uint4*)(vs + (size_t)(r0 + 32) * B + c0);
    }

    for (int tt = t0; tt < t0 + tps; ++tt) {
        __syncthreads();   // prior tile's LDS reads complete
        *(uint4*)&Klds[r0][c0]      = kA;
        *(uint4*)&Klds[r0 + 32][c0] = kB;
        *(uint4*)&Vlds[r0][c0]      = vA;
        *(uint4*)&Vlds[r0 + 32][c0] = vB;
        __syncthreads();

        if (tt + 1 < t0 + tps) {   // prefetch next tile; waits overlap compute
            const unsigned short* ks = kbase + (size_t)((tt + 1) * KVT) * 64;
            const unsigned short* vs = vbase + (size_t)((tt + 1) * KVT);
            kA = *(const uint4*)(ks + (size_t)r0 * 64 + c0);
            kB = *(const uint4*)(ks + (size_t)(r0 + 32) * 64 + c0);
            vA = *(const uint4*)(vs + (size_t)r0 * B + c0);
            vB = *(const uint4*)(vs + (size_t)(r0 + 32) * B + c0);
        }

        // S = Q @ K^T (8 MFMA), P = exp(S) -> LDS
        #pragma unroll
        for (int ct = 0; ct < 4; ++ct) {
            const short8v kb0 = *(const short8v*)&Klds[ct * 16 + lr][kg * 8];
            const short8v kb1 = *(const short8v*)&Klds[ct * 16 + lr][32 + kg * 8];
            f32x4 z = (f32x4){0.f, 0.f, 0.f, 0.f};
            z = __builtin_amdgcn_mfma_f32_16x16x32_bf16(qa0, kb0, z, 0, 0, 0);
            z = __builtin_amdgcn_mfma_f32_16x16x32_bf16(qa1, kb1, z, 0, 0, 0);
            #pragma unroll
            for (int j = 0; j < 4; ++j)
                Plds[wid][kg * 4 + j][ct * 16 + lr] = f2bf(__expf(z[j]));
        }

        // O += P @ V (8 MFMA); V ones-column at d=50 accumulates sum(P)
        const short8v pa0 = *(const short8v*)&Plds[wid][lr][kg * 8];
        const short8v pa1 = *(const short8v*)&Plds[wid][lr][32 + kg * 8];
        #pragma unroll
        for (int ct = 0; ct < 4; ++ct) {
            const short8v vb0 = *(const short8v*)&Vlds[ct * 16 + lr][kg * 8];
            const short8v vb1 = *(const short8v*)&Vlds[ct * 16 + lr][32 + kg * 8];
            oacc[ct] = __builtin_amdgcn_mfma_f32_16x16x32_bf16(pa0, vb0, oacc[ct], 0, 0, 0);
            oacc[ct] = __builtin_amdgcn_mfma_f32_16x16x32_bf16(pa1, vb1, oacc[ct], 0, 0, 0);
        }
    }

    const size_t pbase = (((size_t)(l * QTC + qt) * ns + sp) * TS) * PST;
    #pragma unroll
    for (int j = 0; j < 4; ++j) {
        const int row = wid * 16 + kg * 4 + j;
        const size_t rowb = pbase + (size_t)row * PST;
        #pragma unroll
        for (int ct = 0; ct < 4; ++ct) {
            const int d = ct * 16 + lr;
            if (d < 52) part[rowb + d] = oacc[ct][j];
        }
    }
}

__device__ __forceinline__ void dsp_body(
    unsigned char* sm, int b, int tid,
    const float* __restrict__ emb_ws, const float* __restrict__ Ftab,
    const float* __restrict__ beta,
    const float* __restrict__ ln_w, const float* __restrict__ ln_b,
    float* __restrict__ dsp_ws)
{
    const int wid = tid >> 6, lane = tid & 63;
    float (*se)[D] = (float(*)[D])sm;              // 4000
    float (*sy)[D] = (float(*)[D])(sm + 4000);     // 4000
    float (*F)[L]  = (float(*)[L])(sm + 8000);     // 1600

    for (int i = tid; i < L * D; i += 256) se[i / D][i % D] = emb_ws[(size_t)b * L * D + i];
    for (int i = tid; i < L * L; i += 256) (&F[0][0])[i] = Ftab[i];
    __syncthreads();
    for (int i = tid; i < L * D; i += 256) {
        int l = i / D, d = i % D;
        float low = 0.f;
        #pragma unroll
        for (int t = 0; t < L; ++t) low += F[l][t] * se[t][d];
        float be = beta[d], b2 = be * be;
        sy[l][d] = (1.f - b2) * low + (1.f + b2) * se[l][d];
    }
    __syncthreads();
    for (int l = wid; l < L; l += 4) {
        float x = (lane < D) ? sy[l][lane] : 0.f;
        float s = x;
        #pragma unroll
        for (int mk = 1; mk < 64; mk <<= 1) s += __shfl_xor(s, mk);
        const float mu = s * (1.f / (float)D);
        const float xm = (lane < D) ? (x - mu) : 0.f;
        float v = xm * xm;
        #pragma unroll
        for (int mk = 1; mk < 64; mk <<= 1) v += __shfl_xor(v, mk);
        const float rs = rsqrtf(v * (1.f / (float)D) + 1e-12f);
        if (lane < D)
            dsp_ws[((size_t)b * L + l) * D + lane] = ALPHA * (ln_w[lane] * xm * rs + ln_b[lane]);
    }
}

// ggnn_main with sx reuse (hinp overwrites xin; 26.6 KB LDS).
__device__ __forceinline__ void ggnn_main_body(
    unsigned char* sm, int blk, int tid,
    const unsigned short* __restrict__ hx_bf, const unsigned short* __restrict__ h_bf,
    const unsigned short* __restrict__ wAB_bf, const unsigned short* __restrict__ wrzh_bf,
    const unsigned short* __restrict__ wrz_bf, const unsigned short* __restrict__ wh_bf,
    const float* __restrict__ biasAB, const float* __restrict__ brz_pad,
    const float* __restrict__ brzh_pad, const float* __restrict__ b_h_old,
    float* __restrict__ out_ggnn)
{
    const int wid = tid >> 6, lane = tid & 63;
    const int lr = lane & 15, kg = lane >> 4;
    const int wl = wid * 16;
    const int rblk = blk * 64;

    unsigned short (*sx)[136]  = (unsigned short(*)[136])sm;             // 17408
    unsigned short (*shh)[72]  = (unsigned short(*)[72])(sm + 17408);    // 9216

    for (int i = tid; i < 1024; i += 256) {
        const int r = i >> 4, c = i & 15;
        *(uint4*)&sx[r][c * 8] = *(const uint4*)(hx_bf + ((size_t)(rblk + r)) * 128 + c * 8);
    }
    for (int i = tid; i < 512; i += 256) {
        const int r = i >> 3, c = i & 7;
        *(uint4*)&shh[r][c * 8] = *(const uint4*)(h_bf + ((size_t)(rblk + r)) * 64 + c * 8);
    }
    __syncthreads();

    short8v ax[4];
    #pragma unroll
    for (int t = 0; t < 4; ++t) ax[t] = *(const short8v*)&sx[wl + lr][t * 32 + kg * 8];
    f32x4 acc1[7];
    #pragma unroll
    for (int ct = 0; ct < 7; ++ct) {
        f32x4 z = (f32x4){0.f, 0.f, 0.f, 0.f};
        #pragma unroll
        for (int t = 0; t < 4; ++t) {
            const short8v wb = *(const short8v*)(wAB_bf + ((size_t)(ct * 16 + lr)) * 128 + t * 32 + kg * 8);
            z = __builtin_amdgcn_mfma_f32_16x16x32_bf16(ax[t], wb, z, 0, 0, 0);
        }
        acc1[ct] = z;
    }
    #pragma unroll
    for (int ct = 0; ct < 7; ++ct) {
        const float bb = biasAB[ct * 16 + lr];
        #pragma unroll
        for (int j = 0; j < 4; ++j)
            sx[wl + kg * 4 + j][ct * 16 + lr] = f2bf(acc1[ct][j] + bb);
    }

    short8v ah[4];
    #pragma unroll
    for (int t = 0; t < 4; ++t) ah[t] = *(const short8v*)&sx[wl + lr][t * 32 + kg * 8];
    f32x4 acc2[12];
    #pragma unroll
    for (int ct = 0; ct < 12; ++ct) {
        f32x4 z = (f32x4){0.f, 0.f, 0.f, 0.f};
        #pragma unroll
        for (int t = 0; t < 4; ++t) {
            const short8v wb = *(const short8v*)(wrzh_bf + ((size_t)(ct * 16 + lr)) * 128 + t * 32 + kg * 8);
            z = __builtin_amdgcn_mfma_f32_16x16x32_bf16(ah[t], wb, z, 0, 0, 0);
        }
        acc2[ct] = z;
    }
    short8v ahh[2];
    #pragma unroll
    for (int t = 0; t < 2; ++t) ahh[t] = *(const short8v*)&shh[wl + lr][t * 32 + kg * 8];
    f32x4 acc3[8];
    #pragma unroll
    for (int ct = 0; ct < 8; ++ct) {
        f32x4 z = (f32x4){0.f, 0.f, 0.f, 0.f};
        #pragma unroll
        for (int t = 0; t < 2; ++t) {
            const short8v wb = *(const short8v*)(wrz_bf + ((size_t)(ct * 16 + lr)) * 64 + t * 32 + kg * 8);
            z = __builtin_amdgcn_mfma_f32_16x16x32_bf16(ahh[t], wb, z, 0, 0, 0);
        }
        acc3[ct] = z;
    }

    #pragma unroll
    for (int ct = 0; ct < 4; ++ct) {
        const int e = ct * 16 + lr;
        const float br = brz_pad[e], brh = brzh_pad[e];
        #pragma unroll
        for (int j = 0; j < 4; ++j) {
            const float reset = sigf(acc3[ct][j] + br + acc2[ct][j] + brh);
            const float hval = bf2f(shh[wl + kg * 4 + j][e]);
            sx[wl + kg * 4 + j][e] = f2bf(reset * hval);
        }
    }

    short8v ar[2];
    #pragma unroll
    for (int t = 0; t < 2; ++t) ar[t] = *(const short8v*)&sx[wl + lr][t * 32 + kg * 8];
    f32x4 acc4[4];
    #pragma unroll
    for (int ct = 0; ct < 4; ++ct) {
        f32x4 z = (f32x4){0.f, 0.f, 0.f, 0.f};
        #pragma unroll
        for (int t = 0; t < 2; ++t) {
            const short8v wb = *(const short8v*)(wh_bf + ((size_t)(ct * 16 + lr)) * 64 + t * 32 + kg * 8);
            z = __builtin_amdgcn_mfma_f32_16x16x32_bf16(ar[t], wb, z, 0, 0, 0);
        }
        acc4[ct] = z;
    }

    #pragma unroll
    for (int ct = 0; ct < 4; ++ct) {
        const int e = ct * 16 + lr;
        if (e < 50) {
            const float brz_z = brz_pad[64 + e], brh_z = brzh_pad[64 + e];
            const float brh_h = brzh_pad[128 + e], bh = b_h_old[e];
            #pragma unroll
            for (int j = 0; j < 4; ++j) {
                const int rl = wl + kg * 4 + j;
                const float zg = sigf(acc3[4 + ct][j] + brz_z + acc2[4 + ct][j] + brh_z);
                const float hn = tanhf(acc2[8 + ct][j] + brh_h + acc4[ct][j] + bh);
                const float hval = bf2f(shh[rl][e]);
                out_ggnn[(size_t)(rblk + rl) * D + e] = (1.f - zg) * hval + zg * hn;
            }
        }
    }
}

__global__ __launch_bounds__(256) void stage2_kernel(
    const unsigned short* __restrict__ Qp, const unsigned short* __restrict__ Kp,
    const unsigned short* __restrict__ VTp, float* __restrict__ part,
    int ns, int tps,
    const float* __restrict__ emb_ws, const float* __restrict__ Ftab,
    const float* __restrict__ beta,
    const float* __restrict__ ln_w, const float* __restrict__ ln_b,
    float* __restrict__ dsp_ws,
    const unsigned short* __restrict__ hx_bf, const unsigned short* __restrict__ h_bf,
    const unsigned short* __restrict__ wAB_bf, const unsigned short* __restrict__ wrzh_bf,
    const unsigned short* __restrict__ wrz_bf, const unsigned short* __restrict__ wh_bf,
    const float* __restrict__ biasAB, const float* __restrict__ brz_pad,
    const float* __restrict__ brzh_pad, const float* __restrict__ b_h_old,
    float* __restrict__ out_ggnn)
{
    __shared__ __align__(16) unsigned char sm[K2_SMEM];
    const int bid = blockIdx.x, tid = threadIdx.x;
    const int attnB = 320 * ns;
    if (bid < attnB) {
        // XCD-aware bijective swizzle (attnB % 8 == 0): each XCD gets a
        // contiguous chunk of logical blocks -> same-l K/V panels stay in
        // one XCD's L2 instead of being refetched by all 8.
        const int lb = (bid & 7) * (attnB >> 3) + (bid >> 3);
        const int sp = lb / 320, rem = lb % 320;
        attn_mfma_body(sm, rem % 16, rem / 16, sp, tid, Qp, Kp, VTp, part, ns, tps);
    } else if (bid < attnB + 320) {
        ggnn_main_body(sm, bid - attnB, tid, hx_bf, h_bf, wAB_bf, wrzh_bf,
                       wrz_bf, wh_bf, biasAB, brz_pad, brzh_pad, b_h_old, out_ggnn);
    } else {
        dsp_body(sm, bid - attnB - 320, tid, emb_ws, Ftab, beta, ln_w, ln_b, dsp_ws);
    }
}

// ===========================================================================
// Stage-3 kernel: attn_reduce (320)
// ===========================================================================
__global__ __launch_bounds__(256) void stage3_kernel(
    const float* __restrict__ part,
    const unsigned short* __restrict__ wout_bf, const float* __restrict__ out_b,
    const float* __restrict__ dsp_ws, float* __restrict__ out_hidden, int ns)
{
    const int bid = blockIdx.x, tid = threadIdx.x;
    const int qt = bid % 16, l = bid / 16;
    const int s0 = qt * TS;
    const int wid = tid >> 6, lane = tid & 63;
    const int lr = lane & 15, kg = lane >> 4;
    const int wl = wid * 16;

    __shared__ unsigned short ca[64][72];

    const size_t pbase = ((size_t)(l * QTC + qt) * ns) * TS * PST;

    for (int i = tid; i < 1024; i += 256) {
        const int row = i >> 4, c4 = i & 15;
        const int col = c4 * 4;
        if (col >= 52) {
            ca[row][col] = 0; ca[row][col + 1] = 0;
            ca[row][col + 2] = 0; ca[row][col + 3] = 0;
            continue;
        }
        float4 a = make_float4(0.f, 0.f, 0.f, 0.f);
        float lsum = 0.f;
        for (int sp = 0; sp < ns; ++sp) {
            const size_t rb = pbase + ((size_t)sp * TS + row) * PST;
            lsum += part[rb + 50];
            float4 p = *(const float4*)&part[rb + col];
            a.x += p.x; a.y += p.y; a.z += p.z; a.w += p.w;
        }
        const float inv = 1.f / lsum;
        ca[row][col]     = f2bf(a.x * inv);
        ca[row][col + 1] = f2bf(a.y * inv);
        ca[row][col + 2] = f2bf(a.z * inv);
        ca[row][col + 3] = f2bf(a.w * inv);
    }
    __syncthreads();

    const short8v a0 = *(const short8v*)&ca[wl + lr][kg * 8];
    const short8v a1 = *(const short8v*)&ca[wl + lr][32 + kg * 8];
    f32x4 acc[4];
    #pragma unroll
    for (int ct = 0; ct < 4; ++ct) {
        const unsigned short* wrow = wout_bf + ((size_t)(ct * 16 + lr)) * 64;
        const short8v wb0 = *(const short8v*)(wrow + kg * 8);
        const short8v wb1 = *(const short8v*)(wrow + 32 + kg * 8);
        f32x4 z = (f32x4){0.f, 0.f, 0.f, 0.f};
        z = __builtin_amdgcn_mfma_f32_16x16x32_bf16(a0, wb0, z, 0, 0, 0);
        z = __builtin_amdgcn_mfma_f32_16x16x32_bf16(a1, wb1, z, 0, 0, 0);
        acc[ct] = z;
    }
    #pragma unroll
    for (int ct = 0; ct < 4; ++ct) {
        const int e = ct * 16 + lr;
        if (e < 50) {
            const float bb = out_b[e];
            #pragma unroll
            for (int j = 0; j < 4; ++j) {
                const int s = s0 + wl + kg * 4 + j;
                const size_t base = ((size_t)s * L + l) * D;
                out_hidden[base + e] = dsp_ws[base + e] + (1.f - ALPHA) * (acc[ct][j] + bb);
            }
        }
    }
}

// ---------------------------------------------------------------------------
extern "C" void kernel_launch(void* const* d_in, const int* in_sizes, int n_in,
                              void* d_out, int out_size, void* d_ws, size_t ws_size,
                              hipStream_t stream)
{
    const float* item_emb   = (const float*)d_in[0];
    const float* pop_emb    = (const float*)d_in[1];
    const float* beta       = (const float*)d_in[2];
    const float* ln_w       = (const float*)d_in[3];
    const float* ln_b       = (const float*)d_in[4];
    const float* in_proj_w  = (const float*)d_in[5];
    const float* in_proj_b  = (const float*)d_in[6];
    const float* out_proj_w = (const float*)d_in[7];
    const float* out_proj_b = (const float*)d_in[8];
    const float* w_in       = (const float*)d_in[9];
    const float* b_in       = (const float*)d_in[10];
    const float* w_out      = (const float*)d_in[11];
    const float* b_out      = (const float*)d_in[12];
    const float* w_rzh      = (const float*)d_in[13];
    const float* b_rzh      = (const float*)d_in[14];
    const float* w_rz_old   = (const float*)d_in[15];
    const float* b_rz_old   = (const float*)d_in[16];
    const float* w_h_old    = (const float*)d_in[17];
    const float* b_h_old    = (const float*)d_in[18];
    const float* gat_w      = (const float*)d_in[19];
    const float* gat_b      = (const float*)d_in[20];
    const float* A          = (const float*)d_in[21];
    const float* self_vecs  = (const float*)d_in[22];
    const float* neigh_vecs = (const float*)d_in[23];
    const int* input_session = (const int*)d_in[24];
    const int* input_pop     = (const int*)d_in[25];
    const int* node_items    = (const int*)d_in[26];

    float* ws = (float*)d_ws;
    float* emb_ws = ws;                                   // 1,024,000 f
    float* dsp_ws = ws + (size_t)1024000;                 // 1,024,000 f
    unsigned short* Qp  = (unsigned short*)(ws + 2048000);
    unsigned short* Kp  = Qp + (size_t)L * B * 64;
    unsigned short* VTp = Kp + (size_t)L * B * 64;
    unsigned short* hx_bf = (unsigned short*)(ws + 4014080);    // NR*128 us
    unsigned short* h_bf  = hx_bf + (size_t)NR * 128;           // NR*64 us
    unsigned short* wAB_bf  = h_bf + (size_t)NR * 64;           // 112*128
    unsigned short* wrzh_bf = wAB_bf + 112 * 128;               // 192*128
    unsigned short* wrz_bf  = wrzh_bf + 192 * 128;              // 128*64
    unsigned short* wh_bf   = wrz_bf + 128 * 64;                // 64*64
    float* biasAB   = (float*)(wh_bf + 64 * 64);                // 112
    float* brz_pad  = biasAB + 112;                             // 128
    float* brzh_pad = brz_pad + 128;                            // 192
    unsigned short* wqkv_bf = (unsigned short*)(brzh_pad + 192); // 192*64 us
    unsigned short* wout_bf = wqkv_bf + 192 * 64;                // 64*64 us
    float* biasqkv = (float*)(wout_bf + 64 * 64);                // 192 f
    float* Ftab = biasqkv + 192;                                 // 400 f
    float* gat_wT = Ftab + 400;                                  // 3200 f
    float* part = gat_wT + 3200;

    const size_t base_f = (size_t)(part - ws);
    int ns = 1;
    for (int cand = 4; cand >= 1; cand >>= 1) {
        size_t need = (base_f + (size_t)L * QTC * cand * TS * PST) * 4;
        if (ws_size >= need) { ns = cand; break; }
    }
    const int tps = NKV / ns;   // KV tiles (of 64 rows) per split

    float* out_hidden = (float*)d_out;
    float* out_ggnn   = out_hidden + (size_t)B * L * D;
    float* out_gat    = out_hidden + (size_t)2 * B * L * D;

    prep_weights<<<96, 256, 0, stream>>>(w_in, w_out, w_rzh, w_rz_old, w_h_old,
                                         b_in, b_out, b_rzh, b_rz_old,
                                         in_proj_w, in_proj_b, out_proj_w, gat_w,
                                         wAB_bf, wrzh_bf, wrz_bf, wh_bf,
                                         biasAB, brz_pad, brzh_pad,
                                         wqkv_bf, biasqkv, wout_bf, Ftab, gat_wT);
    stage1_kernel<<<320 + 1024 + (M_GAT / 4), 256, 0, stream>>>(
        item_emb, pop_emb, input_session, input_pop, wqkv_bf, biasqkv,
        emb_ws, Qp, Kp, VTp,
        node_items, A, hx_bf, h_bf,
        self_vecs, neigh_vecs, gat_wT, gat_b, out_gat);
    stage2_kernel<<<320 * ns + 320 + 1024, 256, 0, stream>>>(
        Qp, Kp, VTp, part, ns, tps,
        emb_ws, Ftab, beta, ln_w, ln_b, dsp_ws,
        hx_bf, h_bf, wAB_bf, wrzh_bf, wrz_bf, wh_bf,
        biasAB, brz_pad, brzh_pad, b_h_old, out_ggnn);
    stage3_kernel<<<320, 256, 0, stream>>>(
        part, wout_bf, out_proj_b, dsp_ws, out_hidden, ns);
}